// Round 9
// baseline (173.671 us; speedup 1.0000x reference)
//
#include <hip/hip_runtime.h>
#include <stdint.h>

typedef unsigned short u16;
typedef float  f32x4  __attribute__((ext_vector_type(4)));
typedef float  f32x16 __attribute__((ext_vector_type(16)));
typedef __bf16 bf16x8 __attribute__((ext_vector_type(8)));
typedef __bf16 bf16x4 __attribute__((ext_vector_type(4)));
typedef unsigned short u16x8 __attribute__((ext_vector_type(8)));
typedef unsigned short u16x4v __attribute__((ext_vector_type(4)));

#define S_LEN 2048
#define E_DIM 2048
#define HD    128
#define QH    16
#define KVH   4
#define KVD   512
#define NQKV  3072
#define QK_SCALE 0.08838834764831845f  // 1/sqrt(128)

#define AS1 __attribute__((address_space(1)))
#define AS3 __attribute__((address_space(3)))

__device__ __forceinline__ u16 f2bf(float f) {
  union { float f; uint32_t u; } v; v.f = f;
  return (u16)((v.u + 0x7FFFu + ((v.u >> 16) & 1u)) >> 16);
}
__device__ __forceinline__ float bf2f(u16 b) {
  union { uint32_t u; float f; } v; v.u = ((uint32_t)b) << 16;
  return v.f;
}

// ---------------- fused cast fp32 -> bf16 for all 5 tensors ----------------
__global__ void cast_all_kernel(const float* __restrict__ x, const float* __restrict__ Wq,
                                const float* __restrict__ Wk, const float* __restrict__ Wv,
                                const float* __restrict__ Wo,
                                u16* __restrict__ xb, u16* __restrict__ Wcat,
                                u16* __restrict__ Wob) {
  int i = blockIdx.x * blockDim.x + threadIdx.x;
  const float* src; u16* dst;
  if (i < (1 << 20))                       { src = x  + (size_t)i * 4;  dst = xb + (size_t)i * 4; }
  else if (i < (2 << 20))                  { size_t j = i - (1 << 20);  src = Wq + j * 4; dst = Wcat + j * 4; }
  else if (i < (2 << 20) + (1 << 18))      { size_t j = i - (2 << 20);  src = Wk + j * 4; dst = Wcat + (size_t)E_DIM * E_DIM + j * 4; }
  else if (i < (2 << 20) + (2 << 18))      { size_t j = i - (2 << 20) - (1 << 18); src = Wv + j * 4; dst = Wcat + (size_t)(E_DIM + KVD) * E_DIM + j * 4; }
  else                                     { size_t j = i - (2 << 20) - (2 << 18); src = Wo + j * 4; dst = Wob + j * 4; }
  float4 f = *reinterpret_cast<const float4*>(src);
  u16x4v o;
  o[0] = f2bf(f.x); o[1] = f2bf(f.y); o[2] = f2bf(f.z); o[3] = f2bf(f.w);
  *reinterpret_cast<u16x4v*>(dst) = o;
}

// ---------------- GEMM: C[M,N] = A[M,K] * B[N,K]^T (+bias), bf16 in ----------
template<bool BIAS, bool OBF16>
__global__ __launch_bounds__(256) void gemm_bt_kernel(
    const u16* __restrict__ A, const u16* __restrict__ B,
    void* __restrict__ Cv, const float* __restrict__ bias,
    int M, int N, int K)
{
  __shared__ u16 As[2][128 * 64];
  __shared__ u16 Bs[2][128 * 64];

  const int tid  = threadIdx.x;
  const int lane = tid & 63;
  const int wid  = tid >> 6;
  const int wr   = (wid >> 1) * 64;
  const int wc   = (wid & 1) * 64;
  const int lr   = lane & 15;
  const int kg   = lane >> 4;

  const int bm = blockIdx.y * 128;
  const int bn = blockIdx.x * 128;

  f32x4 acc[4][4];
  #pragma unroll
  for (int r = 0; r < 4; ++r)
    #pragma unroll
    for (int c = 0; c < 4; ++c) acc[r][c] = (f32x4){0.f, 0.f, 0.f, 0.f};

  const int l8 = lane & 7;
  const int l3 = lane >> 3;
  const int schunk = l8 ^ l3;

  const u16* gA = A + (size_t)(bm + wid*32 + l3) * K + schunk * 8;
  const u16* gB = B + (size_t)(bn + wid*32 + l3) * K + schunk * 8;

  const int sw = lr & 7;

  auto stage = [&](int buf, int kt) {
    #pragma unroll
    for (int i = 0; i < 4; ++i) {
      __builtin_amdgcn_global_load_lds(
          (const AS1 void*)(gA + (size_t)i * 8 * K + kt),
          (AS3 void*)(&As[buf][wid*32*64 + i*8*64]), 16, 0, 0);
      __builtin_amdgcn_global_load_lds(
          (const AS1 void*)(gB + (size_t)i * 8 * K + kt),
          (AS3 void*)(&Bs[buf][wid*32*64 + i*8*64]), 16, 0, 0);
    }
  };

  stage(0, 0);
  __syncthreads();

  int cur = 0;
  for (int kt = 0; kt < K; kt += 64) {
    if (kt + 64 < K) stage(cur ^ 1, kt + 64);
    #pragma unroll
    for (int kk = 0; kk < 2; ++kk) {
      bf16x8 af[4], bfr[4];
      #pragma unroll
      for (int r = 0; r < 4; ++r)
        af[r] = *reinterpret_cast<const bf16x8*>(
            &As[cur][(wr + r*16 + lr)*64 + ((kk*4 + kg) ^ sw)*8]);
      #pragma unroll
      for (int c = 0; c < 4; ++c)
        bfr[c] = *reinterpret_cast<const bf16x8*>(
            &Bs[cur][(wc + c*16 + lr)*64 + ((kk*4 + kg) ^ sw)*8]);
      #pragma unroll
      for (int r = 0; r < 4; ++r)
        #pragma unroll
        for (int c = 0; c < 4; ++c)
          acc[r][c] = __builtin_amdgcn_mfma_f32_16x16x32_bf16(af[r], bfr[c], acc[r][c], 0, 0, 0);
    }
    __syncthreads();
    cur ^= 1;
  }

  const int crow = kg * 4;
  #pragma unroll
  for (int r = 0; r < 4; ++r) {
    #pragma unroll
    for (int c = 0; c < 4; ++c) {
      int gr = bm + wr + r*16 + crow;
      int gc = bn + wc + c*16 + lr;
      float badd = BIAS ? bias[gc] : 0.0f;
      #pragma unroll
      for (int reg = 0; reg < 4; ++reg) {
        float v = acc[r][c][reg] + badd;
        if constexpr (OBF16)
          ((u16*)Cv)[(size_t)(gr + reg)*N + gc] = f2bf(v);
        else
          ((float*)Cv)[(size_t)(gr + reg)*N + gc] = v;
      }
    }
  }
}

// ---------------- RoPE + split qkv_bf16 -> q_bf16 (scaled), k_bf16 -------------
__global__ void rope_split_kernel(const u16* __restrict__ qkv,
                                  u16* __restrict__ qb, u16* __restrict__ kb) {
  int idx = blockIdx.x * blockDim.x + threadIdx.x;
  int s  = idx / 1280;
  int cp = idx - s * 1280;
  int col = cp * 2;
  const u16* src = qkv + (size_t)s * NQKV + col;
  float x0 = bf2f(src[0]), x1 = bf2f(src[1]);
  int p = (col & 127) >> 1;
  float inv = exp2f((float)p * (-13.287712379549449f / 64.0f));
  float ang = (float)s * inv;
  float sn, cs;
  sincosf(ang, &sn, &cs);
  float o0 = x0 * cs - x1 * sn;
  float o1 = x0 * sn + x1 * cs;
  if (col < E_DIM) {
    o0 *= QK_SCALE; o1 *= QK_SCALE;
    qb[(size_t)s * E_DIM + col]     = f2bf(o0);
    qb[(size_t)s * E_DIM + col + 1] = f2bf(o1);
  } else {
    kb[(size_t)s * KVD + (col - E_DIM)]     = f2bf(o0);
    kb[(size_t)s * KVD + (col - E_DIM) + 1] = f2bf(o1);
  }
}

// ---------------- V transpose: qkv bf16 v-block (S x 512) -> vT (512 x S) ------
__global__ void transpose_v_kernel(const u16* __restrict__ qkv, u16* __restrict__ vT) {
  __shared__ u16 tile[32][33];
  const int sbase = blockIdx.x * 32;
  const int cbase = blockIdx.y * 32;
  const int tx = threadIdx.x;
  const int ty = threadIdx.y;
  #pragma unroll
  for (int i = 0; i < 32; i += 8)
    tile[ty + i][tx] = qkv[(size_t)(sbase + ty + i) * NQKV + (E_DIM + KVD) + cbase + tx];
  __syncthreads();
  #pragma unroll
  for (int i = 0; i < 32; i += 8)
    vT[(size_t)(cbase + ty + i) * S_LEN + sbase + tx] = tile[tx][ty + i];
}

// ---------------- Flash attention (causal, GQA 4:1), 32x32 MFMA core -----------
// 512 blocks x 128 threads (2 waves x 32 q-rows), r7 shell: flip-paired qt,
// K dbuf via global_load_lds w16 (src XOR swizzle), V reg-dbuf -> swizzled VTs,
// swapped QK^T (mfma(K,Q)) in-register softmax, defer-max THR=8, Ps P-routing.
// 32x32x16 frags: 2x FLOP per LDS byte and per instruction vs 16x16x32.
// LDS 57.2 KB -> 2 blocks/CU.
__global__ __launch_bounds__(128) void attn_kernel(
    const u16* __restrict__ Q, const u16* __restrict__ Kc,
    const u16* __restrict__ VT, u16* __restrict__ Out)
{
  __shared__ u16 Ks[2][64 * 128];   // [kv][d] 16KB x2
  __shared__ u16 VTs[128 * 64];     // [d][kv] 16KB
  __shared__ u16 Ps[2][32 * 72];    // per-wave P [q][kv], 144B rows

  const int x    = blockIdx.x;
  const int pp   = x >> 1;
  const int base = pp & 15;
  const int h    = (pp >> 4) & 15;
  const int flip = (x ^ (x >> 8)) & 1;
  const int qt   = flip ? 31 - base : base;
  const int kvh  = h >> 2;

  const int tid  = threadIdx.x;
  const int lane = tid & 63;
  const int wid  = tid >> 6;    // 0..1, q rows wid*32..+32
  const int ln   = lane & 31;   // row/col index within 32x32 frags
  const int hi   = lane >> 5;   // k-half selector

  const int NT = qt + 1;

  // Q B-frags: col=q=ln, k=(hi)*8+j per 16-wide k-step; 8 ksteps over D=128
  bf16x8 qf[8];
  {
    const u16* qa = Q + (size_t)(qt*64 + wid*32 + ln) * E_DIM + h * HD + hi * 8;
    #pragma unroll
    for (int ks = 0; ks < 8; ++ks)
      qf[ks] = *reinterpret_cast<const bf16x8*>(qa + ks * 16);
  }

  f32x16 o4[4];   // 4 d-tiles of 32x32 (q x d)
  #pragma unroll
  for (int d = 0; d < 4; ++d)
    #pragma unroll
    for (int r = 0; r < 16; ++r) o4[d][r] = 0.f;
  float mr = -1e30f, ls = 0.f;

  const u16* kbase = Kc + kvh * HD;
  const u16* vbase = VT + (size_t)(kvh * HD) * S_LEN;
  u16* ps = Ps[wid];

  // K tile DMA (16KB, 128 thr): wave w issue j covers rows j*8+w*4..+4.
  // lane l -> row +(l>>4), LDS chunk l&15; src chunk = (l&15)^(row&7).
  const int kr_off = lane >> 4;
  const int kchunk = lane & 15;
  auto k_dma = [&](int buf, int t) {
    #pragma unroll
    for (int j = 0; j < 8; ++j) {
      int r0 = j*8 + wid*4;
      int r  = r0 + kr_off;
      const u16* src = kbase + (size_t)(t*64 + r) * KVD + ((kchunk ^ (r & 7)) * 8);
      __builtin_amdgcn_global_load_lds((const AS1 void*)src,
          (AS3 void*)(&Ks[buf][r0 * 128]), 16, 0, 0);
    }
  };

  // V global->reg (coalesced along kv); reg->VTs with chunk^(d&7).
  u16x8 vreg[8];
  auto v_load = [&](int t) {
    #pragma unroll
    for (int i = 0; i < 8; ++i) {
      int c = i * 128 + tid;
      vreg[i] = *reinterpret_cast<const u16x8*>(
          vbase + (size_t)(c >> 3) * S_LEN + t*64 + (c & 7) * 8);
    }
  };
  auto v_write = [&]() {
    #pragma unroll
    for (int i = 0; i < 8; ++i) {
      int c = i * 128 + tid;
      int d = c >> 3;
      *reinterpret_cast<u16x8*>(&VTs[d*64 + ((c & 7) ^ (d & 7)) * 8]) = vreg[i];
    }
  };

  k_dma(0, 0);
  v_load(0);
  v_write();
  __syncthreads();

  int p = 0;
  for (int t = 0; t < NT; ++t) {
    const bool lastt = (t + 1 == NT);
    if (!lastt) { k_dma(p ^ 1, t + 1); v_load(t + 1); }

    // S^T = mfma(K, Q): out[kv][q], col=ln=q, row=(reg&3)+8*(reg>>2)+4*hi
    f32x16 st[2];
    #pragma unroll
    for (int c = 0; c < 2; ++c)
      #pragma unroll
      for (int r = 0; r < 16; ++r) st[c][r] = 0.f;
    __builtin_amdgcn_s_setprio(1);
    #pragma unroll
    for (int ks = 0; ks < 8; ++ks) {
      #pragma unroll
      for (int c = 0; c < 2; ++c) {
        int row = c*32 + ln;
        bf16x8 kfr = *reinterpret_cast<const bf16x8*>(
            &Ks[p][row*128 + ((ks*2 + hi) ^ (row & 7))*8]);
        st[c] = __builtin_amdgcn_mfma_f32_32x32x16_bf16(kfr, qf[ks], st[c], 0, 0, 0);
      }
    }
    __builtin_amdgcn_s_setprio(0);

    if (t == qt) {  // causal: mask kv_local > q_local
      #pragma unroll
      for (int c = 0; c < 2; ++c)
        #pragma unroll
        for (int reg = 0; reg < 16; ++reg) {
          int kvl = c*32 + (reg & 3) + 8*(reg >> 2) + 4*hi;
          if (kvl > wid*32 + ln) st[c][reg] = -1e30f;
        }
    }

    // row max for q=ln: in-register tree over 32 + 1 cross-half shfl
    float pm = -1e30f;
    #pragma unroll
    for (int c = 0; c < 2; ++c)
      #pragma unroll
      for (int reg = 0; reg < 16; ++reg) pm = fmaxf(pm, st[c][reg]);
    pm = fmaxf(pm, __shfl_xor(pm, 32));

    if (!__all(pm - mr <= 8.0f)) {  // defer-max rescale (rare)
      float nm = fmaxf(mr, pm);
      float alpha = __expf(mr - nm);
      ls *= alpha;
      mr = nm;
      #pragma unroll
      for (int reg = 0; reg < 16; ++reg) {
        int crow = (reg & 3) + 8*(reg >> 2) + 4*hi;  // q-row of o4[*][reg]
        float ar = __shfl(alpha, crow);
        #pragma unroll
        for (int d = 0; d < 4; ++d) o4[d][reg] *= ar;
      }
    }

    // exp, sum, pack P -> Ps[q=ln][kv] (4 consecutive kv per b64)
    float sum = 0.f;
    #pragma unroll
    for (int c = 0; c < 2; ++c) {
      #pragma unroll
      for (int rg = 0; rg < 4; ++rg) {
        float pr[4];
        #pragma unroll
        for (int j = 0; j < 4; ++j)
          pr[j] = __expf(st[c][rg*4 + j] - mr);
        sum += (pr[0] + pr[1]) + (pr[2] + pr[3]);
        bf16x4 pk;
        #pragma unroll
        for (int j = 0; j < 4; ++j) pk[j] = (__bf16)pr[j];
        *reinterpret_cast<bf16x4*>(&ps[ln*72 + c*32 + rg*8 + hi*4]) = pk;
      }
    }
    sum += __shfl_xor(sum, 32);
    ls += sum;

    // O += P * V: A=P (row=q=ln, k=kv), B=V (col=d=ln, k=kv)
    bf16x8 pa[4];
    #pragma unroll
    for (int ks = 0; ks < 4; ++ks)
      pa[ks] = *reinterpret_cast<const bf16x8*>(&ps[ln*72 + ks*16 + hi*8]);
    __builtin_amdgcn_s_setprio(1);
    #pragma unroll
    for (int d = 0; d < 4; ++d) {
      #pragma unroll
      for (int ks = 0; ks < 4; ++ks) {
        int row = d*32 + ln;
        bf16x8 vb = *reinterpret_cast<const bf16x8*>(
            &VTs[row*64 + ((ks*2 + hi) ^ (row & 7))*8]);
        o4[d] = __builtin_amdgcn_mfma_f32_32x32x16_bf16(pa[ks], vb, o4[d], 0, 0, 0);
      }
    }
    __builtin_amdgcn_s_setprio(0);

    if (!lastt) {
      __syncthreads();   // waves done with VTs(t)/Ks[p]; drains K-DMA(t+1)
      v_write();         // V(t+1) -> VTs
      __syncthreads();   // VTs(t+1) visible
      p ^= 1;
    }
  }

  // epilogue: normalize rows (inv lives on lane q=ln; o4 rows are crow(reg,hi))
  {
    float inv = 1.0f / ls;
    #pragma unroll
    for (int reg = 0; reg < 16; ++reg) {
      int crow = (reg & 3) + 8*(reg >> 2) + 4*hi;
      float iv = __shfl(inv, crow);
      int grow = qt*64 + wid*32 + crow;
      #pragma unroll
      for (int d = 0; d < 4; ++d)
        Out[(size_t)grow * E_DIM + h * HD + d*32 + ln] =
            __builtin_bit_cast(u16, (__bf16)(o4[d][reg] * iv));
    }
  }
}

// ---------------- launch ----------------
extern "C" void kernel_launch(void* const* d_in, const int* in_sizes, int n_in,
                              void* d_out, int out_size, void* d_ws, size_t ws_size,
                              hipStream_t stream)
{
  const float* x  = (const float*)d_in[0];
  const float* Wq = (const float*)d_in[1];
  const float* Wk = (const float*)d_in[2];
  const float* Wv = (const float*)d_in[3];
  const float* Wo = (const float*)d_in[4];
  const float* bo = (const float*)d_in[5];
  float* out = (float*)d_out;

  char* w = (char*)d_ws;
  u16*   xb   = (u16*)(w);                   // 8 MB  x bf16 (2048x2048)
  u16*   Wcat = (u16*)(w + (8u  << 20));     // 12 MB [Wq;Wk;Wv] bf16 (3072x2048)
  u16*   Wob  = (u16*)(w + (20u << 20));     // 8 MB  Wo bf16
  u16*   qkv  = (u16*)(w + (28u << 20));     // 12 MB qkv bf16 (2048x3072)
  u16*   qb   = (u16*)(w + (52u << 20));     // 8 MB  q bf16 roped+scaled
  u16*   kb   = (u16*)(w + (60u << 20));     // 2 MB  k bf16 roped
  u16*   vT   = (u16*)(w + (62u << 20));     // 2 MB  v^T bf16 (512x2048)
  u16*   attn = (u16*)(w + (64u << 20));     // 8 MB  attention out bf16
  (void)ws_size; (void)in_sizes; (void)n_in; (void)out_size;

  cast_all_kernel<<<14336, 256, 0, stream>>>(x, Wq, Wk, Wv, Wo, xb, Wcat, Wob);

  gemm_bt_kernel<false, true><<<dim3(NQKV/128, S_LEN/128), 256, 0, stream>>>(
      xb, Wcat, qkv, nullptr, S_LEN, NQKV, E_DIM);

  rope_split_kernel<<<(S_LEN * 1280) / 256, 256, 0, stream>>>(qkv, qb, kb);
  transpose_v_kernel<<<dim3(S_LEN/32, KVD/32), dim3(32, 8), 0, stream>>>(qkv, vT);

  attn_kernel<<<512, 128, 0, stream>>>(qb, kb, vT, attn);

  gemm_bt_kernel<true, false><<<dim3(E_DIM/128, S_LEN/128), 256, 0, stream>>>(
      attn, Wob, out, bo, S_LEN, E_DIM, E_DIM);
}

// Round 10
// 139.880 us; speedup vs baseline: 1.2416x; 1.2416x over previous
//
#include <hip/hip_runtime.h>
#include <stdint.h>

typedef unsigned short u16;
typedef float  f32x4  __attribute__((ext_vector_type(4)));
typedef __bf16 bf16x8 __attribute__((ext_vector_type(8)));
typedef __bf16 bf16x4 __attribute__((ext_vector_type(4)));
typedef unsigned short u16x8 __attribute__((ext_vector_type(8)));
typedef unsigned short u16x4v __attribute__((ext_vector_type(4)));

#define S_LEN 2048
#define E_DIM 2048
#define HD    128
#define QH    16
#define KVH   4
#define KVD   512
#define NQKV  3072
#define QK_SCALE 0.08838834764831845f  // 1/sqrt(128)

#define AS1 __attribute__((address_space(1)))
#define AS3 __attribute__((address_space(3)))

__device__ __forceinline__ u16 f2bf(float f) {
  union { float f; uint32_t u; } v; v.f = f;
  return (u16)((v.u + 0x7FFFu + ((v.u >> 16) & 1u)) >> 16);
}
__device__ __forceinline__ float bf2f(u16 b) {
  union { uint32_t u; float f; } v; v.u = ((uint32_t)b) << 16;
  return v.f;
}

// ---------------- fused cast fp32 -> bf16 for all 5 tensors ----------------
__global__ void cast_all_kernel(const float* __restrict__ x, const float* __restrict__ Wq,
                                const float* __restrict__ Wk, const float* __restrict__ Wv,
                                const float* __restrict__ Wo,
                                u16* __restrict__ xb, u16* __restrict__ Wcat,
                                u16* __restrict__ Wob) {
  int i = blockIdx.x * blockDim.x + threadIdx.x;
  const float* src; u16* dst;
  if (i < (1 << 20))                       { src = x  + (size_t)i * 4;  dst = xb + (size_t)i * 4; }
  else if (i < (2 << 20))                  { size_t j = i - (1 << 20);  src = Wq + j * 4; dst = Wcat + j * 4; }
  else if (i < (2 << 20) + (1 << 18))      { size_t j = i - (2 << 20);  src = Wk + j * 4; dst = Wcat + (size_t)E_DIM * E_DIM + j * 4; }
  else if (i < (2 << 20) + (2 << 18))      { size_t j = i - (2 << 20) - (1 << 18); src = Wv + j * 4; dst = Wcat + (size_t)(E_DIM + KVD) * E_DIM + j * 4; }
  else                                     { size_t j = i - (2 << 20) - (2 << 18); src = Wo + j * 4; dst = Wob + j * 4; }
  float4 f = *reinterpret_cast<const float4*>(src);
  u16x4v o;
  o[0] = f2bf(f.x); o[1] = f2bf(f.y); o[2] = f2bf(f.z); o[3] = f2bf(f.w);
  *reinterpret_cast<u16x4v*>(dst) = o;
}

// ---------------- GEMM: C[M,N] = A[M,K] * B[N,K]^T (+bias), bf16 in ----------
// 128x128 tile, BK=64, 512 threads = 8 waves (2x4, each owns 64x32).
// 2-phase dbuf, global_load_lds w16 issued for t+1 before compute of t,
// source-side XOR swizzle -> conflict-free b128 reads. 8 waves/CU resident
// even at 1 block/CU (occupancy fix for small grids). OBF16: bf16 C output.
template<bool BIAS, bool OBF16>
__global__ __launch_bounds__(512) void gemm_bt_kernel(
    const u16* __restrict__ A, const u16* __restrict__ B,
    void* __restrict__ Cv, const float* __restrict__ bias,
    int M, int N, int K)
{
  __shared__ u16 As[2][128 * 64];
  __shared__ u16 Bs[2][128 * 64];

  const int tid  = threadIdx.x;
  const int lane = tid & 63;
  const int wid  = tid >> 6;           // 0..7
  const int wr   = (wid >> 2) * 64;    // 2 wave-rows
  const int wc   = (wid & 3) * 32;     // 4 wave-cols
  const int lr   = lane & 15;
  const int kg   = lane >> 4;
  const int sw   = lr & 7;

  const int bm = blockIdx.y * 128;
  const int bn = blockIdx.x * 128;

  f32x4 acc[4][2];
  #pragma unroll
  for (int r = 0; r < 4; ++r)
    #pragma unroll
    for (int c = 0; c < 2; ++c) acc[r][c] = (f32x4){0.f, 0.f, 0.f, 0.f};

  // staging: wave w covers rows w*8..+8 (+64 per issue); lane l -> row
  // w*8+(l>>3), LDS slot l&7; source chunk = (l&7)^(l>>3)  (== slot^(row&7)).
  const int srow   = wid * 8 + (lane >> 3);
  const int schunk = (lane & 7) ^ (lane >> 3);

  const u16* gA = A + (size_t)(bm + srow) * K + schunk * 8;
  const u16* gB = B + (size_t)(bn + srow) * K + schunk * 8;

  auto stage = [&](int buf, int kt) {
    #pragma unroll
    for (int i = 0; i < 2; ++i) {
      __builtin_amdgcn_global_load_lds(
          (const AS1 void*)(gA + (size_t)i * 64 * K + kt),
          (AS3 void*)(&As[buf][(wid*8 + i*64) * 64]), 16, 0, 0);
      __builtin_amdgcn_global_load_lds(
          (const AS1 void*)(gB + (size_t)i * 64 * K + kt),
          (AS3 void*)(&Bs[buf][(wid*8 + i*64) * 64]), 16, 0, 0);
    }
  };

  stage(0, 0);
  __syncthreads();

  int cur = 0;
  for (int kt = 0; kt < K; kt += 64) {
    if (kt + 64 < K) stage(cur ^ 1, kt + 64);  // in flight across the MFMAs
    #pragma unroll
    for (int kk = 0; kk < 2; ++kk) {
      bf16x8 af[4], bfr[2];
      #pragma unroll
      for (int r = 0; r < 4; ++r)
        af[r] = *reinterpret_cast<const bf16x8*>(
            &As[cur][(wr + r*16 + lr)*64 + ((kk*4 + kg) ^ sw)*8]);
      #pragma unroll
      for (int c = 0; c < 2; ++c)
        bfr[c] = *reinterpret_cast<const bf16x8*>(
            &Bs[cur][(wc + c*16 + lr)*64 + ((kk*4 + kg) ^ sw)*8]);
      #pragma unroll
      for (int r = 0; r < 4; ++r)
        #pragma unroll
        for (int c = 0; c < 2; ++c)
          acc[r][c] = __builtin_amdgcn_mfma_f32_16x16x32_bf16(af[r], bfr[c], acc[r][c], 0, 0, 0);
    }
    __syncthreads();
    cur ^= 1;
  }

  const int crow = kg * 4;
  #pragma unroll
  for (int r = 0; r < 4; ++r) {
    #pragma unroll
    for (int c = 0; c < 2; ++c) {
      int gr = bm + wr + r*16 + crow;
      int gc = bn + wc + c*16 + lr;
      float badd = BIAS ? bias[gc] : 0.0f;
      #pragma unroll
      for (int reg = 0; reg < 4; ++reg) {
        float v = acc[r][c][reg] + badd;
        if constexpr (OBF16)
          ((u16*)Cv)[(size_t)(gr + reg)*N + gc] = f2bf(v);
        else
          ((float*)Cv)[(size_t)(gr + reg)*N + gc] = v;
      }
    }
  }
}

// ---------------- RoPE + split qkv_bf16 -> q_bf16 (scaled), k_bf16 -------------
__global__ void rope_split_kernel(const u16* __restrict__ qkv,
                                  u16* __restrict__ qb, u16* __restrict__ kb) {
  int idx = blockIdx.x * blockDim.x + threadIdx.x;
  int s  = idx / 1280;
  int cp = idx - s * 1280;
  int col = cp * 2;
  const u16* src = qkv + (size_t)s * NQKV + col;
  float x0 = bf2f(src[0]), x1 = bf2f(src[1]);
  int p = (col & 127) >> 1;
  float inv = exp2f((float)p * (-13.287712379549449f / 64.0f));
  float ang = (float)s * inv;
  float sn, cs;
  sincosf(ang, &sn, &cs);
  float o0 = x0 * cs - x1 * sn;
  float o1 = x0 * sn + x1 * cs;
  if (col < E_DIM) {
    o0 *= QK_SCALE; o1 *= QK_SCALE;
    qb[(size_t)s * E_DIM + col]     = f2bf(o0);
    qb[(size_t)s * E_DIM + col + 1] = f2bf(o1);
  } else {
    kb[(size_t)s * KVD + (col - E_DIM)]     = f2bf(o0);
    kb[(size_t)s * KVD + (col - E_DIM) + 1] = f2bf(o1);
  }
}

// ---------------- V transpose: qkv bf16 v-block (S x 512) -> vT (512 x S) ------
__global__ void transpose_v_kernel(const u16* __restrict__ qkv, u16* __restrict__ vT) {
  __shared__ u16 tile[32][33];
  const int sbase = blockIdx.x * 32;
  const int cbase = blockIdx.y * 32;
  const int tx = threadIdx.x;
  const int ty = threadIdx.y;
  #pragma unroll
  for (int i = 0; i < 32; i += 8)
    tile[ty + i][tx] = qkv[(size_t)(sbase + ty + i) * NQKV + (E_DIM + KVD) + cbase + tx];
  __syncthreads();
  #pragma unroll
  for (int i = 0; i < 32; i += 8)
    vT[(size_t)(cbase + ty + i) * S_LEN + sbase + tx] = tile[tx][ty + i];
}

// ---------------- Flash attention tile, SWAPPED QK^T (r4-proven, 50.3us) -------
__device__ __forceinline__ void attn_tile(
    int t, int qt, int wid, int lr, int kg,
    const bf16x8* qf, f32x4* o, float& mr, float& ls,
    const u16* ks, const u16* vts, u16* ps)
{
  const int sw = lr & 7;
  f32x4 st[4];
  #pragma unroll
  for (int c = 0; c < 4; ++c) st[c] = (f32x4){0.f, 0.f, 0.f, 0.f};
  __builtin_amdgcn_s_setprio(1);
  #pragma unroll
  for (int kk = 0; kk < 4; ++kk) {
    #pragma unroll
    for (int c = 0; c < 4; ++c) {
      bf16x8 kfr = *reinterpret_cast<const bf16x8*>(
          &ks[(c*16 + lr)*128 + ((kk*4 + kg) ^ sw)*8]);
      st[c] = __builtin_amdgcn_mfma_f32_16x16x32_bf16(kfr, qf[kk], st[c], 0, 0, 0);
    }
  }
  __builtin_amdgcn_s_setprio(0);
  if (t == qt) {  // causal: mask kv > q (local coords)
    #pragma unroll
    for (int c = 0; c < 4; ++c)
      #pragma unroll
      for (int reg = 0; reg < 4; ++reg)
        if (c*16 + kg*4 + reg > wid*16 + lr) st[c][reg] = -1e30f;
  }
  float cm[4];
  #pragma unroll
  for (int c = 0; c < 4; ++c)
    cm[c] = fmaxf(fmaxf(st[c][0], st[c][1]), fmaxf(st[c][2], st[c][3]));
  float pm = fmaxf(fmaxf(cm[0], cm[1]), fmaxf(cm[2], cm[3]));
  pm = fmaxf(pm, __shfl_xor(pm, 16));
  pm = fmaxf(pm, __shfl_xor(pm, 32));

  if (!__all(pm - mr <= 8.0f)) {  // defer-max: rare after first tile
    float nm = fmaxf(mr, pm);
    float alpha = __expf(mr - nm);
    ls *= alpha;
    mr = nm;
    float ar[4];
    #pragma unroll
    for (int reg = 0; reg < 4; ++reg)
      ar[reg] = __shfl(alpha, kg*4 + reg);
    #pragma unroll
    for (int d = 0; d < 8; ++d)
      #pragma unroll
      for (int reg = 0; reg < 4; ++reg)
        o[d][reg] *= ar[reg];
  }

  float p[4][4];
  float csum[4];
  #pragma unroll
  for (int c = 0; c < 4; ++c) {
    #pragma unroll
    for (int reg = 0; reg < 4; ++reg)
      p[c][reg] = __expf(st[c][reg] - mr);
    csum[c] = (p[c][0] + p[c][1]) + (p[c][2] + p[c][3]);
  }
  float sum = (csum[0] + csum[1]) + (csum[2] + csum[3]);
  sum += __shfl_xor(sum, 16);
  sum += __shfl_xor(sum, 32);
  ls += sum;

  #pragma unroll
  for (int c = 0; c < 4; ++c) {
    bf16x4 pk;
    #pragma unroll
    for (int reg = 0; reg < 4; ++reg) pk[reg] = (__bf16)p[c][reg];
    *reinterpret_cast<bf16x4*>(&ps[lr*72 + c*16 + kg*4]) = pk;
  }
  __builtin_amdgcn_s_setprio(1);
  #pragma unroll
  for (int kk = 0; kk < 2; ++kk) {
    bf16x8 pa = *reinterpret_cast<const bf16x8*>(&ps[lr*72 + kk*32 + kg*8]);
    #pragma unroll
    for (int d = 0; d < 8; ++d) {
      bf16x8 vb = *reinterpret_cast<const bf16x8*>(
          &vts[(d*16 + lr)*64 + ((kk*4 + kg) ^ sw)*8]);
      o[d] = __builtin_amdgcn_mfma_f32_16x16x32_bf16(pa, vb, o[d], 0, 0, 0);
    }
  }
  __builtin_amdgcn_s_setprio(0);
}

// ---------------- Flash attention (causal, GQA 4:1) -- r4-proven config --------
__global__ __launch_bounds__(256, 2) void attn_kernel(
    const u16* __restrict__ Q, const u16* __restrict__ Kc,
    const u16* __restrict__ VT, u16* __restrict__ Out)
{
  __shared__ u16 Ks[2][64 * 128];
  __shared__ u16 VTs[2][128 * 64];
  __shared__ u16 Ps[4][16 * 72];

  const int x = blockIdx.x;
  int qt, h;
  if (x < 256) { qt = x & 31; h = x >> 5; }
  else         { int xp = x - 256; qt = 31 - (xp & 31); h = 8 + (xp >> 5); }
  const int kvh = h >> 2;
  const int tid  = threadIdx.x;
  const int lane = tid & 63;
  const int wid  = tid >> 6;
  const int lr   = lane & 15;
  const int kg   = lane >> 4;

  const int NT = qt + 1;

  bf16x8 qf[4];
  {
    const u16* qa = Q + (size_t)(qt*64 + wid*16 + lr) * E_DIM + h * HD + kg * 8;
    #pragma unroll
    for (int kk = 0; kk < 4; ++kk)
      qf[kk] = *reinterpret_cast<const bf16x8*>(qa + kk * 32);
  }

  f32x4 o[8];
  #pragma unroll
  for (int d = 0; d < 8; ++d) o[d] = (f32x4){0.f,0.f,0.f,0.f};
  float mr = -1e30f, ls = 0.f;

  u16x8 kreg[4], vreg[4];
  const u16* kbase = Kc + kvh * HD;
  const u16* vbase = VT + (size_t)(kvh * HD) * S_LEN;

  auto stage_load = [&](int t) {
    #pragma unroll
    for (int i = 0; i < 4; ++i) {
      int c = i * 256 + tid;
      kreg[i] = *reinterpret_cast<const u16x8*>(
          kbase + (size_t)(t*64 + (c >> 4)) * KVD + (c & 15) * 8);
      vreg[i] = *reinterpret_cast<const u16x8*>(
          vbase + (size_t)(c >> 3) * S_LEN + t*64 + (c & 7) * 8);
    }
  };
  auto stage_write = [&](int b) {
    #pragma unroll
    for (int i = 0; i < 4; ++i) {
      int c = i * 256 + tid;
      int kr = c >> 4, kc = c & 15;
      *reinterpret_cast<u16x8*>(&Ks[b][kr*128 + (kc ^ (kr & 7))*8]) = kreg[i];
      int vr = c >> 3, vc = c & 7;
      *reinterpret_cast<u16x8*>(&VTs[b][vr*64 + (vc ^ (vr & 7))*8]) = vreg[i];
    }
  };

  int p = 0;
  stage_load(0);
  stage_write(0);
  __syncthreads();

  for (int t = 0; t < NT; ++t) {
    if (t + 1 < NT) stage_load(t + 1);  // issue early: latency hides under MFMAs
    attn_tile(t, qt, wid, lr, kg, qf, o, mr, ls, Ks[p], VTs[p], Ps[wid]);
    if (t + 1 < NT) {
      stage_write(p ^ 1);  // vmcnt wait lands here, after compute
      __syncthreads();     // single barrier per tile
      p ^= 1;
    }
  }

  {
    float inv = 1.0f / ls;  // for q = lr
    float ivq[4];
    #pragma unroll
    for (int reg = 0; reg < 4; ++reg)
      ivq[reg] = __shfl(inv, kg*4 + reg);
    #pragma unroll
    for (int reg = 0; reg < 4; ++reg) {
      int grow = qt*64 + wid*16 + kg*4 + reg;
      #pragma unroll
      for (int d = 0; d < 8; ++d)
        Out[(size_t)grow * E_DIM + h * HD + d*16 + lr] =
            __builtin_bit_cast(u16, (__bf16)(o[d][reg] * ivq[reg]));
    }
  }
}

// ---------------- launch ----------------
extern "C" void kernel_launch(void* const* d_in, const int* in_sizes, int n_in,
                              void* d_out, int out_size, void* d_ws, size_t ws_size,
                              hipStream_t stream)
{
  const float* x  = (const float*)d_in[0];
  const float* Wq = (const float*)d_in[1];
  const float* Wk = (const float*)d_in[2];
  const float* Wv = (const float*)d_in[3];
  const float* Wo = (const float*)d_in[4];
  const float* bo = (const float*)d_in[5];
  float* out = (float*)d_out;

  char* w = (char*)d_ws;
  u16*   xb   = (u16*)(w);                   // 8 MB  x bf16 (2048x2048)
  u16*   Wcat = (u16*)(w + (8u  << 20));     // 12 MB [Wq;Wk;Wv] bf16 (3072x2048)
  u16*   Wob  = (u16*)(w + (20u << 20));     // 8 MB  Wo bf16
  u16*   qkv  = (u16*)(w + (28u << 20));     // 12 MB qkv bf16 (2048x3072)
  u16*   qb   = (u16*)(w + (52u << 20));     // 8 MB  q bf16 roped+scaled
  u16*   kb   = (u16*)(w + (60u << 20));     // 2 MB  k bf16 roped
  u16*   vT   = (u16*)(w + (62u << 20));     // 2 MB  v^T bf16 (512x2048)
  u16*   attn = (u16*)(w + (64u << 20));     // 8 MB  attention out bf16
  (void)ws_size; (void)in_sizes; (void)n_in; (void)out_size;

  cast_all_kernel<<<14336, 256, 0, stream>>>(x, Wq, Wk, Wv, Wo, xb, Wcat, Wob);

  gemm_bt_kernel<false, true><<<dim3(NQKV/128, S_LEN/128), 512, 0, stream>>>(
      xb, Wcat, qkv, nullptr, S_LEN, NQKV, E_DIM);

  rope_split_kernel<<<(S_LEN * 1280) / 256, 256, 0, stream>>>(qkv, qb, kb);
  transpose_v_kernel<<<dim3(S_LEN/32, KVD/32), dim3(32, 8), 0, stream>>>(qkv, vT);

  attn_kernel<<<512, 256, 0, stream>>>(qb, kb, vT, attn);

  gemm_bt_kernel<true, false><<<dim3(E_DIM/128, S_LEN/128), 512, 0, stream>>>(
      attn, Wob, out, bo, S_LEN, E_DIM, E_DIM);
}